// Round 5
// baseline (158.697 us; speedup 1.0000x reference)
//
#include <hip/hip_runtime.h>

// Problem constants (fixed by setup_inputs)
constexpr int NB  = 4;     // batch
constexpr int NPT = 2048;  // points (N)
constexpr int KNN = 32;    // neighbors (K)
constexpr int CIN = 6;     // in_channels
constexpr int CF  = 64;    // feat channels
constexpr int CO  = 64;    // out channels
constexpr float EPS = 1e-5f;

typedef short bf16x8 __attribute__((ext_vector_type(8)));   // 8 bf16 in 4 VGPRs
typedef float f32x4  __attribute__((ext_vector_type(4)));

// ---------------- workspace layout (bytes) ----------------
constexpr size_t WS_WA  = 0;       // WAf bf16[6*4*2*64*8] (sa-folded, row-permuted)
constexpr size_t WS_WL  = 49152;   // WLf bf16[4*2*64*8]  (sl-folded)
constexpr size_t WS_WR  = 57344;   // WRf bf16[4*2*64*8]  (sr-folded)
constexpr size_t WS_BA  = 65536;   // baP f32[6*64]
constexpr size_t WS_BNF = 67072;   // bnf f32[3*64]  (s1, b1, blr)

__device__ __host__ inline unsigned short bf16_rne(float f) {
  unsigned u = __builtin_bit_cast(unsigned, f);
  u += 0x7fffu + ((u >> 16) & 1u);
  return (unsigned short)(u >> 16);
}

__global__ void setup_kernel(const float *Wattn, const float *Wlin, const float *Wres,
                             const float *ga, const float *ba, const float *ma, const float *va,
                             const float *g1, const float *b1, const float *m1, const float *v1,
                             const float *gl, const float *bl, const float *ml, const float *vl,
                             const float *gr, const float *br, const float *mr, const float *vr,
                             unsigned short *WAf, unsigned short *WLf, unsigned short *WRf,
                             float *baP, float *bnf) {
  const int t = blockIdx.x * blockDim.x + threadIdx.x;
  const int stride = gridDim.x * blockDim.x;
  for (int e = t; e < 6 * 4 * 2 * 64 * 8; e += stride) {
    const int j = e & 7, l = (e >> 3) & 63, ks = (e >> 9) & 1, ot = (e >> 10) & 3, i = e >> 12;
    const int m = l & 15, cg = l >> 4;
    const int cc = ks * 32 + cg * 8 + j;
    const int row = (ot * 16 + m) * CIN + i;
    const float sa = ga[row] * rsqrtf(va[row] + EPS);
    WAf[e] = bf16_rne(Wattn[row * CF + cc] * sa);
  }
  for (int e = t; e < 4 * 2 * 64 * 8; e += stride) {
    const int j = e & 7, l = (e >> 3) & 63, ks = (e >> 9) & 1, ot = e >> 10;
    const int m = l & 15;
    const int cc = ks * 32 + (l >> 4) * 8 + j;
    const int row = ot * 16 + m;
    const float sl = gl[row] * rsqrtf(vl[row] + EPS);
    const float sr = gr[row] * rsqrtf(vr[row] + EPS);
    WLf[e] = bf16_rne(Wlin[row * CF + cc] * sl);
    WRf[e] = bf16_rne(Wres[row * CF + cc] * sr);
  }
  for (int e = t; e < 384; e += stride) {
    const int i = e >> 6, o = e & 63;
    const int j0 = o * CIN + i;
    const float sa = ga[j0] * rsqrtf(va[j0] + EPS);
    baP[e] = ba[j0] - ma[j0] * sa;
  }
  for (int e = t; e < 64; e += stride) {
    const float s1v = g1[e] * rsqrtf(v1[e] + EPS);
    bnf[e]      = s1v;
    bnf[64 + e] = b1[e] - m1[e] * s1v;
    const float slv = gl[e] * rsqrtf(vl[e] + EPS);
    const float srv = gr[e] * rsqrtf(vr[e] + EPS);
    bnf[128 + e] = (bl[e] - ml[e] * slv) + (br[e] - mr[e] * srv);
  }
}

struct Params {
  const float *x, *y, *points, *feat;
  const float *Wq, *Wpos1, *Wpos2;
  const float *gq, *bq, *mq, *vq;
  const float *gp, *bp, *mp, *vp;
  const unsigned short *WAf, *WLf, *WRf;
  const float *baP, *bnf;
  float *out;
};

// Block = 4 waves, processes 4 points per iteration (2 iterations).
// Phase A: each wave stages + softmaxes its own point (no cross-wave deps).
// Phase B: wave w owns output o-tile w; its Wattn fragments live in registers
// for the whole kernel (48 VGPRs) -> weight L2 streaming per point eliminated.
__global__ __launch_bounds__(256, 4) void fused_pt_attn(Params p) {
  const int tid  = threadIdx.x;
  const int lane = tid & 63;
  const int wv   = tid >> 6;
  // XCD-aware swizzle over 1024 blocks (8 XCDs x 128 contiguous).
  const int bid  = ((blockIdx.x & 7) << 7) | (blockIdx.x >> 3);
  const int p0   = bid * 8;                 // 8 points per block (2 iters x 4)
  const int b    = p0 >> 11;                // same batch for whole block
  const int nb0  = p0 & (NPT - 1);

  __shared__ unsigned short s_P[4][2048];   // P (softmax) -> h, per point
  __shared__ unsigned short s_Y[4][2048];   // y bf16 frags, per point
  __shared__ float s_x[4][192];             // x[i][k] per point
  __shared__ float s_d[4][192];             // d = pos1 - x per point
  __shared__ float s_f[4][32];              // feat per point

  const int og = lane >> 4, kl = lane & 15;
  const int swz = (kl & 7) << 3;

  // ---- persistent weight fragments for this wave's o-tile ----
  const bf16x8 *WAv = (const bf16x8 *)p.WAf;
  bf16x8 WA[6][2];
#pragma unroll
  for (int i = 0; i < 6; ++i)
#pragma unroll
    for (int ks = 0; ks < 2; ++ks)
      WA[i][ks] = WAv[((i * 4 + wv) * 2 + ks) * 64 + lane];

  // loop-invariant staging regs
  const float *w2p = p.Wpos2 + lane * 6;
  const float2 w2a = *(const float2 *)(w2p);
  const float2 w2b = *(const float2 *)(w2p + 2);
  const float2 w2c = *(const float2 *)(w2p + 4);
  const float w2[6] = {w2a.x, w2a.y, w2b.x, w2b.y, w2c.x, w2c.y};

  for (int it = 0; it < 2; ++it) {
    __syncthreads();  // protect buffers from previous iteration's readers

    // ================= Phase A: stage + softmax own point =================
    {
      const int n = nb0 + it * 4 + wv;
      unsigned short *PB = s_P[wv];
      unsigned short *YB = s_Y[wv];
      float *dW = s_d[wv], *xW = s_x[wv], *fW = s_f[wv];

      float ftv = 0.f, ptv = 0.f;
      if (lane < 32) ftv = p.feat[((size_t)b * 32 + lane) * NPT + n];
      if (lane < 3)  ptv = p.points[((size_t)b * 3 + lane) * NPT + n];
      const int xi = lane >> 3, xk = (lane & 7) * 4;
      float4 x4 = make_float4(0.f, 0.f, 0.f, 0.f);
      if (lane < 48)
        x4 = *(const float4 *)(p.x + (((size_t)b * CIN + xi) * NPT + n) * KNN + xk);

      if (lane < 32) fW[lane] = ftv;

      // pos1 (all lanes)
      const float pt0 = __shfl(ptv, 0), pt1 = __shfl(ptv, 1), pt2 = __shfl(ptv, 2);
      float pos1[6];
#pragma unroll
      for (int i = 0; i < 6; ++i) {
        const float a = p.Wpos1[i * 3 + 0] * pt0 + p.Wpos1[i * 3 + 1] * pt1 +
                        p.Wpos1[i * 3 + 2] * pt2;
        const float s = p.gp[i] * rsqrtf(p.vp[i] + EPS);
        const float v = fmaf(a, s, p.bp[i] - p.mp[i] * s);
        pos1[i] = v > 0.f ? v : 0.2f * v;
      }

      // d = pos1 - x ; also stash raw x
      if (lane < 48) {
        float pi = pos1[0];
        pi = (xi == 1) ? pos1[1] : pi;
        pi = (xi == 2) ? pos1[2] : pi;
        pi = (xi == 3) ? pos1[3] : pi;
        pi = (xi == 4) ? pos1[4] : pi;
        pi = (xi == 5) ? pos1[5] : pi;
        *(float4 *)(dW + xi * 32 + xk) =
            make_float4(pi - x4.x, pi - x4.y, pi - x4.z, pi - x4.w);
        *(float4 *)(xW + xi * 32 + xk) = x4;
      }

      // x_q[lane]
      float xq;
      {
        float acc = 0.f;
        const float *wq = p.Wq + lane * 32;
#pragma unroll
        for (int q = 0; q < 8; ++q) {
          const float4 w4 = *(const float4 *)(wq + q * 4);
          const float4 f4 = *(const float4 *)(fW + q * 4);
          acc = fmaf(w4.x, f4.x, fmaf(w4.y, f4.y, fmaf(w4.z, f4.z, fmaf(w4.w, f4.w, acc))));
        }
        const float s = p.gq[lane] * rsqrtf(p.vq[lane] + EPS);
        const float v = fmaf(acc, s, p.bq[lane] - p.mq[lane] * s);
        xq = v > 0.f ? v : 0.2f * v;
      }

      // pre[k] = sum_i w2[i]*d[i][k]
      float pre[32];
#pragma unroll
      for (int k = 0; k < 32; ++k) pre[k] = 0.f;
#pragma unroll
      for (int i = 0; i < 6; ++i) {
        const float wvv = w2[i];
#pragma unroll
        for (int q = 0; q < 8; ++q) {
          const float4 d4 = *(const float4 *)(dW + i * 32 + q * 4);
          pre[q * 4 + 0] = fmaf(wvv, d4.x, pre[q * 4 + 0]);
          pre[q * 4 + 1] = fmaf(wvv, d4.y, pre[q * 4 + 1]);
          pre[q * 4 + 2] = fmaf(wvv, d4.z, pre[q * 4 + 2]);
          pre[q * 4 + 3] = fmaf(wvv, d4.w, pre[q * 4 + 3]);
        }
      }

      // stream y, stash bf16 frags, finalize pre
      const float *yrow = p.y + (((size_t)b * CF + lane) * NPT + n) * KNN;
#pragma unroll
      for (int q = 0; q < 8; ++q) {
        const float4 y4 = *(const float4 *)(yrow + q * 4);
        const float yv[4] = {y4.x, y4.y, y4.z, y4.w};
#pragma unroll
        for (int j = 0; j < 4; ++j) {
          const int k = q * 4 + j;
          YB[k * 64 + (lane ^ ((k & 7) << 3))] = bf16_rne(yv[j]);
          pre[k] = (xq - yv[j] + pre[k]) * 0.125f;
        }
      }

      // in-lane softmax, write P
      float mx = pre[0];
#pragma unroll
      for (int k = 1; k < 32; ++k) mx = fmaxf(mx, pre[k]);
      float sum = 0.f;
#pragma unroll
      for (int k = 0; k < 32; ++k) { pre[k] = __expf(pre[k] - mx); sum += pre[k]; }
      const float inv = 1.f / sum;
#pragma unroll
      for (int k = 0; k < 32; ++k)
        PB[k * 64 + (lane ^ ((k & 7) << 3))] = bf16_rne(pre[k] * inv);
    }
    __syncthreads();  // bar1: all points staged

    // ================= Phase B1: GEMM1 (own o-tile, all 4 points) =========
    uint2 hp[4][2];  // packed h per point (static index!)
    {
      const f32x4 s14 = *(const f32x4 *)(p.bnf + 0 * 64 + wv * 16 + og * 4);
      const f32x4 b14 = *(const f32x4 *)(p.bnf + 1 * 64 + wv * 16 + og * 4);
#pragma unroll
      for (int qq = 0; qq < 4; ++qq) {
        const int q = (qq + wv) & 3;
        const unsigned short *Pq = s_P[q];
        const float *xWq = s_x[q];
        bf16x8 Ba[2][2];
#pragma unroll
        for (int ks = 0; ks < 2; ++ks)
#pragma unroll
          for (int nt = 0; nt < 2; ++nt)
            Ba[ks][nt] = *(const bf16x8 *)(Pq + (kl + nt * 16) * 64 +
                                           ((ks * 32 + og * 8) ^ swz));
        f32x4 o0 = {0.f, 0.f, 0.f, 0.f}, o1 = o0;
#pragma unroll
        for (int i = 0; i < 6; ++i) {
          const f32x4 ba4 = *(const f32x4 *)(p.baP + i * 64 + wv * 16 + og * 4);
          const float xv0 = xWq[i * 32 + kl];
          const float xv1 = xWq[i * 32 + kl + 16];
          f32x4 g = {0.f, 0.f, 0.f, 0.f};
          g = __builtin_amdgcn_mfma_f32_16x16x32_bf16(WA[i][0], Ba[0][0], g, 0, 0, 0);
          g = __builtin_amdgcn_mfma_f32_16x16x32_bf16(WA[i][1], Ba[1][0], g, 0, 0, 0);
#pragma unroll
          for (int r = 0; r < 4; ++r) o0[r] = fmaf(g[r] + ba4[r], xv0, o0[r]);
          g = (f32x4){0.f, 0.f, 0.f, 0.f};
          g = __builtin_amdgcn_mfma_f32_16x16x32_bf16(WA[i][0], Ba[0][1], g, 0, 0, 0);
          g = __builtin_amdgcn_mfma_f32_16x16x32_bf16(WA[i][1], Ba[1][1], g, 0, 0, 0);
#pragma unroll
          for (int r = 0; r < 4; ++r) o1[r] = fmaf(g[r] + ba4[r], xv1, o1[r]);
        }
#pragma unroll
        for (int nt = 0; nt < 2; ++nt) {
          const f32x4 &oo = nt ? o1 : o0;
          unsigned hb[4];
#pragma unroll
          for (int r = 0; r < 4; ++r) {
            const float t = fmaf(s14[r], oo[r], b14[r]);
            hb[r] = bf16_rne(t > 0.f ? t : 0.2f * t);
          }
          hp[qq][nt] = make_uint2(hb[0] | (hb[1] << 16), hb[2] | (hb[3] << 16));
        }
      }
    }
    __syncthreads();  // bar2: all P reads done -> safe to overwrite with h

#pragma unroll
    for (int qq = 0; qq < 4; ++qq) {
      const int q = (qq + wv) & 3;
      unsigned short *Pq = s_P[q];
#pragma unroll
      for (int nt = 0; nt < 2; ++nt)
        *(uint2 *)(Pq + (kl + nt * 16) * 64 + ((wv * 16 + og * 4) ^ swz)) = hp[qq][nt];
    }
    __syncthreads();  // bar3: h visible

    // ================= Phase B2: GEMM2 (own o-tile, all 4 points) =========
    {
      const bf16x8 *WLv = (const bf16x8 *)p.WLf;
      const bf16x8 *WRv = (const bf16x8 *)p.WRf;
      const bf16x8 L0 = WLv[(wv * 2 + 0) * 64 + lane];
      const bf16x8 L1 = WLv[(wv * 2 + 1) * 64 + lane];
      const bf16x8 R0 = WRv[(wv * 2 + 0) * 64 + lane];
      const bf16x8 R1 = WRv[(wv * 2 + 1) * 64 + lane];
      const f32x4 blr = *(const f32x4 *)(p.bnf + 2 * 64 + wv * 16 + og * 4);
#pragma unroll
      for (int qq = 0; qq < 4; ++qq) {
        const int q = (qq + wv) & 3;
        const int nq = nb0 + it * 4 + q;
        const unsigned short *Pq = s_P[q];
        const unsigned short *Yq = s_Y[q];
#pragma unroll
        for (int nt = 0; nt < 2; ++nt) {
          const int off0 = (kl + nt * 16) * 64 + ((0 * 32 + og * 8) ^ swz);
          const int off1 = (kl + nt * 16) * 64 + ((1 * 32 + og * 8) ^ swz);
          const bf16x8 Bh0 = *(const bf16x8 *)(Pq + off0);
          const bf16x8 Bh1 = *(const bf16x8 *)(Pq + off1);
          const bf16x8 By0 = *(const bf16x8 *)(Yq + off0);
          const bf16x8 By1 = *(const bf16x8 *)(Yq + off1);
          f32x4 a = {0.f, 0.f, 0.f, 0.f};
          a = __builtin_amdgcn_mfma_f32_16x16x32_bf16(L0, Bh0, a, 0, 0, 0);
          a = __builtin_amdgcn_mfma_f32_16x16x32_bf16(L1, Bh1, a, 0, 0, 0);
          a = __builtin_amdgcn_mfma_f32_16x16x32_bf16(R0, By0, a, 0, 0, 0);
          a = __builtin_amdgcn_mfma_f32_16x16x32_bf16(R1, By1, a, 0, 0, 0);
          float *ob = p.out + (((size_t)(b * CO + wv * 16 + og * 4)) * NPT + nq) * KNN +
                      kl + nt * 16;
#pragma unroll
          for (int r = 0; r < 4; ++r) {
            const float v = a[r] + blr[r];
            ob[(size_t)r * NPT * KNN] = v > 0.f ? v : 0.2f * v;
          }
        }
      }
    }
  }
}

extern "C" void kernel_launch(void *const *d_in, const int *in_sizes, int n_in,
                              void *d_out, int out_size, void *d_ws, size_t ws_size,
                              hipStream_t stream) {
  char *ws = (char *)d_ws;
  unsigned short *WAf = (unsigned short *)(ws + WS_WA);
  unsigned short *WLf = (unsigned short *)(ws + WS_WL);
  unsigned short *WRf = (unsigned short *)(ws + WS_WR);
  float *baP = (float *)(ws + WS_BA);
  float *bnf = (float *)(ws + WS_BNF);

  setup_kernel<<<dim3(96), dim3(256), 0, stream>>>(
      (const float *)d_in[7], (const float *)d_in[8], (const float *)d_in[9],
      (const float *)d_in[18], (const float *)d_in[19], (const float *)d_in[20], (const float *)d_in[21],
      (const float *)d_in[22], (const float *)d_in[23], (const float *)d_in[24], (const float *)d_in[25],
      (const float *)d_in[26], (const float *)d_in[27], (const float *)d_in[28], (const float *)d_in[29],
      (const float *)d_in[30], (const float *)d_in[31], (const float *)d_in[32], (const float *)d_in[33],
      WAf, WLf, WRf, baP, bnf);

  Params p;
  p.x      = (const float *)d_in[0];
  p.y      = (const float *)d_in[1];
  p.points = (const float *)d_in[2];
  p.feat   = (const float *)d_in[3];
  p.Wq     = (const float *)d_in[4];
  p.Wpos1  = (const float *)d_in[5];
  p.Wpos2  = (const float *)d_in[6];
  p.gq = (const float *)d_in[10]; p.bq = (const float *)d_in[11];
  p.mq = (const float *)d_in[12]; p.vq = (const float *)d_in[13];
  p.gp = (const float *)d_in[14]; p.bp = (const float *)d_in[15];
  p.mp = (const float *)d_in[16]; p.vp = (const float *)d_in[17];
  p.WAf = WAf; p.WLf = WLf; p.WRf = WRf;
  p.baP = baP; p.bnf = bnf;
  p.out = (float *)d_out;

  fused_pt_attn<<<dim3(NB * NPT / 8), dim3(256), 0, stream>>>(p);
}

// Round 6
// 70.160 us; speedup vs baseline: 2.2619x; 2.2619x over previous
//
#include <hip/hip_runtime.h>

// Problem constants (fixed by setup_inputs)
constexpr int NB  = 4;     // batch
constexpr int NPT = 2048;  // points (N)
constexpr int KNN = 32;    // neighbors (K)
constexpr int CIN = 6;     // in_channels
constexpr int CF  = 64;    // feat channels
constexpr int CO  = 64;    // out channels
constexpr float EPS = 1e-5f;

typedef short bf16x8 __attribute__((ext_vector_type(8)));   // 8 bf16 in 4 VGPRs
typedef float f32x4  __attribute__((ext_vector_type(4)));

// ---------------- workspace layout (bytes) ----------------
constexpr size_t WS_WA  = 0;       // WAf bf16[6*4*2*64*8] (sa-folded, row-permuted)
constexpr size_t WS_WL  = 49152;   // WLf bf16[4*2*64*8]  (sl-folded)
constexpr size_t WS_WR  = 57344;   // WRf bf16[4*2*64*8]  (sr-folded)
constexpr size_t WS_BA  = 65536;   // baP f32[6*64]
constexpr size_t WS_BNF = 67072;   // bnf f32[3*64]  (s1, b1, blr)

__device__ __host__ inline unsigned short bf16_rne(float f) {
  unsigned u = __builtin_bit_cast(unsigned, f);
  u += 0x7fffu + ((u >> 16) & 1u);
  return (unsigned short)(u >> 16);
}

__global__ void setup_kernel(const float *Wattn, const float *Wlin, const float *Wres,
                             const float *ga, const float *ba, const float *ma, const float *va,
                             const float *g1, const float *b1, const float *m1, const float *v1,
                             const float *gl, const float *bl, const float *ml, const float *vl,
                             const float *gr, const float *br, const float *mr, const float *vr,
                             unsigned short *WAf, unsigned short *WLf, unsigned short *WRf,
                             float *baP, float *bnf) {
  const int t = blockIdx.x * blockDim.x + threadIdx.x;
  const int stride = gridDim.x * blockDim.x;
  for (int e = t; e < 6 * 4 * 2 * 64 * 8; e += stride) {
    const int j = e & 7, l = (e >> 3) & 63, ks = (e >> 9) & 1, ot = (e >> 10) & 3, i = e >> 12;
    const int m = l & 15, cg = l >> 4;
    const int cc = ks * 32 + cg * 8 + j;
    const int row = (ot * 16 + m) * CIN + i;
    const float sa = ga[row] * rsqrtf(va[row] + EPS);
    WAf[e] = bf16_rne(Wattn[row * CF + cc] * sa);
  }
  for (int e = t; e < 4 * 2 * 64 * 8; e += stride) {
    const int j = e & 7, l = (e >> 3) & 63, ks = (e >> 9) & 1, ot = e >> 10;
    const int m = l & 15;
    const int cc = ks * 32 + (l >> 4) * 8 + j;
    const int row = ot * 16 + m;
    const float sl = gl[row] * rsqrtf(vl[row] + EPS);
    const float sr = gr[row] * rsqrtf(vr[row] + EPS);
    WLf[e] = bf16_rne(Wlin[row * CF + cc] * sl);
    WRf[e] = bf16_rne(Wres[row * CF + cc] * sr);
  }
  for (int e = t; e < 384; e += stride) {
    const int i = e >> 6, o = e & 63;
    const int j0 = o * CIN + i;
    const float sa = ga[j0] * rsqrtf(va[j0] + EPS);
    baP[e] = ba[j0] - ma[j0] * sa;
  }
  for (int e = t; e < 64; e += stride) {
    const float s1v = g1[e] * rsqrtf(v1[e] + EPS);
    bnf[e]      = s1v;
    bnf[64 + e] = b1[e] - m1[e] * s1v;
    const float slv = gl[e] * rsqrtf(vl[e] + EPS);
    const float srv = gr[e] * rsqrtf(vr[e] + EPS);
    bnf[128 + e] = (bl[e] - ml[e] * slv) + (br[e] - mr[e] * srv);
  }
}

struct Params {
  const float *x, *y, *points, *feat;
  const float *Wq, *Wpos1, *Wpos2;
  const float *gq, *bq, *mq, *vq;
  const float *gp, *bp, *mp, *vp;
  const unsigned short *WAf, *WLf, *WRf;
  const float *baP, *bnf;
  float *out;
};

// One wave per point; no block barriers. ONE 4KB bf16 B-buffer per wave,
// recycled y -> P(unnormalized exp) -> h; y-fragments hoisted to registers
// before P overwrites (in-wave DS FIFO ordering makes this safe; validated R4).
// 1/sum is folded into GEMM1's bias combine instead of normalizing P.
__global__ __launch_bounds__(256) void fused_pt_attn(Params p) {
  const int tid  = threadIdx.x;
  const int lane = tid & 63;
  const int wid  = tid >> 6;
  // XCD-aware swizzle: 2048 blocks, 8 XCDs -> each XCD gets a contiguous range.
  const int bid  = ((blockIdx.x & 7) << 8) + (blockIdx.x >> 3);
  const int pidx = bid * 4 + wid;
  const int b    = pidx >> 11;
  const int n    = pidx & (NPT - 1);

  __shared__ unsigned short s_B[4][2048];   // recycled frag buffer per wave
  __shared__ float s_d[4][192];             // d = pos1 - x
  __shared__ float s_f[4][32];              // feat
  unsigned short *BB = s_B[wid];
  float *dW = s_d[wid];
  float *fW = s_f[wid];

  // ---- stage: issue global loads ----
  float ftv = 0.f, ptv = 0.f;
  if (lane < 32) ftv = p.feat[((size_t)b * 32 + lane) * NPT + n];
  if (lane < 3)  ptv = p.points[((size_t)b * 3 + lane) * NPT + n];
  const int xi = lane >> 3, xk = (lane & 7) * 4;
  float4 x4 = make_float4(0.f, 0.f, 0.f, 0.f);
  if (lane < 48)
    x4 = *(const float4 *)(p.x + (((size_t)b * CIN + xi) * NPT + n) * KNN + xk);
  const float *w2p = p.Wpos2 + lane * 6;   // Wpos2[c][i], row per lane channel
  const float2 w2a = *(const float2 *)(w2p);
  const float2 w2b = *(const float2 *)(w2p + 2);
  const float2 w2c = *(const float2 *)(w2p + 4);
  const float w2[6] = {w2a.x, w2a.y, w2b.x, w2b.y, w2c.x, w2c.y};

  if (lane < 32) fW[lane] = ftv;

  // ---- pos1 (all lanes) ----
  const float pt0 = __shfl(ptv, 0), pt1 = __shfl(ptv, 1), pt2 = __shfl(ptv, 2);
  float pos1[6];
#pragma unroll
  for (int i = 0; i < 6; ++i) {
    const float a = p.Wpos1[i * 3 + 0] * pt0 + p.Wpos1[i * 3 + 1] * pt1 +
                    p.Wpos1[i * 3 + 2] * pt2;
    const float s = p.gp[i] * rsqrtf(p.vp[i] + EPS);
    const float v = fmaf(a, s, p.bp[i] - p.mp[i] * s);
    pos1[i] = v > 0.f ? v : 0.2f * v;
  }

  // ---- d[i][k] = pos1[i] - x[i][k] ----
  if (lane < 48) {
    float pi = pos1[0];
    pi = (xi == 1) ? pos1[1] : pi;
    pi = (xi == 2) ? pos1[2] : pi;
    pi = (xi == 3) ? pos1[3] : pi;
    pi = (xi == 4) ? pos1[4] : pi;
    pi = (xi == 5) ? pos1[5] : pi;
    *(float4 *)(dW + xi * 32 + xk) =
        make_float4(pi - x4.x, pi - x4.y, pi - x4.z, pi - x4.w);
  }

  // ---- x_q[lane] ----
  float xq;
  {
    float acc = 0.f;
    const float *wq = p.Wq + lane * 32;
#pragma unroll
    for (int q = 0; q < 8; ++q) {
      const float4 w4 = *(const float4 *)(wq + q * 4);
      const float4 f4 = *(const float4 *)(fW + q * 4);
      acc = fmaf(w4.x, f4.x, fmaf(w4.y, f4.y, fmaf(w4.z, f4.z, fmaf(w4.w, f4.w, acc))));
    }
    const float s = p.gq[lane] * rsqrtf(p.vq[lane] + EPS);
    const float v = fmaf(acc, s, p.bq[lane] - p.mq[lane] * s);
    xq = v > 0.f ? v : 0.2f * v;
  }

  // ---- pre[k] = sum_i w2[i]*d[i][k] ----
  float pre[32];
#pragma unroll
  for (int k = 0; k < 32; ++k) pre[k] = 0.f;
#pragma unroll
  for (int i = 0; i < 6; ++i) {
    const float wv = w2[i];
#pragma unroll
    for (int q = 0; q < 8; ++q) {
      const float4 d4 = *(const float4 *)(dW + i * 32 + q * 4);
      pre[q * 4 + 0] = fmaf(wv, d4.x, pre[q * 4 + 0]);
      pre[q * 4 + 1] = fmaf(wv, d4.y, pre[q * 4 + 1]);
      pre[q * 4 + 2] = fmaf(wv, d4.z, pre[q * 4 + 2]);
      pre[q * 4 + 3] = fmaf(wv, d4.w, pre[q * 4 + 3]);
    }
  }

  // ---- stream y: stash bf16 frags in BB, finalize pre ----
  const float *yrow = p.y + (((size_t)b * CF + lane) * NPT + n) * KNN;
#pragma unroll
  for (int q = 0; q < 8; ++q) {
    const float4 y4 = *(const float4 *)(yrow + q * 4);
    const float yv[4] = {y4.x, y4.y, y4.z, y4.w};
#pragma unroll
    for (int j = 0; j < 4; ++j) {
      const int k = q * 4 + j;
      BB[k * 64 + (lane ^ ((k & 7) << 3))] = bf16_rne(yv[j]);
      pre[k] = (xq - yv[j] + pre[k]) * 0.125f;
    }
  }

  const int og = lane >> 4, kl = lane & 15;
  const int swz = (kl & 7) << 3;

  // ---- hoist y B-fragments to regs (before P overwrites the buffer) ----
  bf16x8 By[2][2];
#pragma unroll
  for (int ks = 0; ks < 2; ++ks)
#pragma unroll
    for (int nt = 0; nt < 2; ++nt)
      By[ks][nt] = *(const bf16x8 *)(BB + (kl + nt * 16) * 64 +
                                     ((ks * 32 + og * 8) ^ swz));

  // ---- in-lane softmax: write UNNORMALIZED exp over y; inv folded later ----
  float mx = pre[0];
#pragma unroll
  for (int k = 1; k < 32; ++k) mx = fmaxf(mx, pre[k]);
  float sum = 0.f;
#pragma unroll
  for (int k = 0; k < 32; ++k) {
    pre[k] = __expf(pre[k] - mx);
    BB[k * 64 + (lane ^ ((k & 7) << 3))] = bf16_rne(pre[k]);
    sum += pre[k];
  }
  const float inv = 1.f / sum;

  // ---- x values for the combine: x[i][kcol] = pos1[i] - d[i][kcol] ----
  float xvv[6][2];
#pragma unroll
  for (int i = 0; i < 6; ++i)
#pragma unroll
    for (int nt = 0; nt < 2; ++nt)
      xvv[i][nt] = pos1[i] - dW[i * 32 + kl + nt * 16];

  // ---- P B-fragments (unnormalized) ----
  bf16x8 Ba[2][2];
#pragma unroll
  for (int ks = 0; ks < 2; ++ks)
#pragma unroll
    for (int nt = 0; nt < 2; ++nt)
      Ba[ks][nt] = *(const bf16x8 *)(BB + (kl + nt * 16) * 64 +
                                     ((ks * 32 + og * 8) ^ swz));

  // ---- GEMM1 per o-tile: g*inv + ba, x-combine, BN1+lrelu, h over P ----
  const bf16x8 *WAv = (const bf16x8 *)p.WAf;
#pragma unroll
  for (int ot = 0; ot < 4; ++ot) {
    float out1[2][4] = {{0.f, 0.f, 0.f, 0.f}, {0.f, 0.f, 0.f, 0.f}};
#pragma unroll
    for (int i = 0; i < 6; ++i) {
      const bf16x8 A0 = WAv[((i * 4 + ot) * 2 + 0) * 64 + lane];
      const bf16x8 A1 = WAv[((i * 4 + ot) * 2 + 1) * 64 + lane];
      const f32x4 ba4 = *(const f32x4 *)(p.baP + i * 64 + ot * 16 + og * 4);
#pragma unroll
      for (int nt = 0; nt < 2; ++nt) {
        f32x4 g = {0.f, 0.f, 0.f, 0.f};
        g = __builtin_amdgcn_mfma_f32_16x16x32_bf16(A0, Ba[0][nt], g, 0, 0, 0);
        g = __builtin_amdgcn_mfma_f32_16x16x32_bf16(A1, Ba[1][nt], g, 0, 0, 0);
        const float xv = xvv[i][nt];
#pragma unroll
        for (int r = 0; r < 4; ++r)
          out1[nt][r] = fmaf(fmaf(g[r], inv, ba4[r]), xv, out1[nt][r]);
      }
    }
    const f32x4 s14 = *(const f32x4 *)(p.bnf + 0 * 64 + ot * 16 + og * 4);
    const f32x4 b14 = *(const f32x4 *)(p.bnf + 1 * 64 + ot * 16 + og * 4);
#pragma unroll
    for (int nt = 0; nt < 2; ++nt) {
      const int kcol = kl + nt * 16;
      unsigned hp[4];
#pragma unroll
      for (int r = 0; r < 4; ++r) {
        const float t = fmaf(s14[r], out1[nt][r], b14[r]);
        hp[r] = bf16_rne(t > 0.f ? t : 0.2f * t);
      }
      const int idx = kcol * 64 + ((ot * 16 + og * 4) ^ swz);
      *(uint2 *)(BB + idx) = make_uint2(hp[0] | (hp[1] << 16), hp[2] | (hp[3] << 16));
    }
  }

  // ---- GEMM2: out = lrelu( Wlin'@h + Wres'@y + blr ) ----
  bf16x8 Bh[2][2];
#pragma unroll
  for (int ks = 0; ks < 2; ++ks)
#pragma unroll
    for (int nt = 0; nt < 2; ++nt)
      Bh[ks][nt] = *(const bf16x8 *)(BB + (kl + nt * 16) * 64 +
                                     ((ks * 32 + og * 8) ^ swz));

  const bf16x8 *WLv = (const bf16x8 *)p.WLf;
  const bf16x8 *WRv = (const bf16x8 *)p.WRf;
#pragma unroll
  for (int ot = 0; ot < 4; ++ot) {
    const bf16x8 L0 = WLv[(ot * 2 + 0) * 64 + lane];
    const bf16x8 L1 = WLv[(ot * 2 + 1) * 64 + lane];
    const bf16x8 R0 = WRv[(ot * 2 + 0) * 64 + lane];
    const bf16x8 R1 = WRv[(ot * 2 + 1) * 64 + lane];
    const f32x4 blr = *(const f32x4 *)(p.bnf + 2 * 64 + ot * 16 + og * 4);
#pragma unroll
    for (int nt = 0; nt < 2; ++nt) {
      f32x4 a = {0.f, 0.f, 0.f, 0.f};
      a = __builtin_amdgcn_mfma_f32_16x16x32_bf16(L0, Bh[0][nt], a, 0, 0, 0);
      a = __builtin_amdgcn_mfma_f32_16x16x32_bf16(L1, Bh[1][nt], a, 0, 0, 0);
      a = __builtin_amdgcn_mfma_f32_16x16x32_bf16(R0, By[0][nt], a, 0, 0, 0);
      a = __builtin_amdgcn_mfma_f32_16x16x32_bf16(R1, By[1][nt], a, 0, 0, 0);
      const int kcol = kl + nt * 16;
      float *ob = p.out + (((size_t)(b * CO + ot * 16 + og * 4)) * NPT + n) * KNN + kcol;
#pragma unroll
      for (int r = 0; r < 4; ++r) {
        const float v = a[r] + blr[r];
        ob[(size_t)r * NPT * KNN] = v > 0.f ? v : 0.2f * v;
      }
    }
  }
}

extern "C" void kernel_launch(void *const *d_in, const int *in_sizes, int n_in,
                              void *d_out, int out_size, void *d_ws, size_t ws_size,
                              hipStream_t stream) {
  char *ws = (char *)d_ws;
  unsigned short *WAf = (unsigned short *)(ws + WS_WA);
  unsigned short *WLf = (unsigned short *)(ws + WS_WL);
  unsigned short *WRf = (unsigned short *)(ws + WS_WR);
  float *baP = (float *)(ws + WS_BA);
  float *bnf = (float *)(ws + WS_BNF);

  setup_kernel<<<dim3(96), dim3(256), 0, stream>>>(
      (const float *)d_in[7], (const float *)d_in[8], (const float *)d_in[9],
      (const float *)d_in[18], (const float *)d_in[19], (const float *)d_in[20], (const float *)d_in[21],
      (const float *)d_in[22], (const float *)d_in[23], (const float *)d_in[24], (const float *)d_in[25],
      (const float *)d_in[26], (const float *)d_in[27], (const float *)d_in[28], (const float *)d_in[29],
      (const float *)d_in[30], (const float *)d_in[31], (const float *)d_in[32], (const float *)d_in[33],
      WAf, WLf, WRf, baP, bnf);

  Params p;
  p.x      = (const float *)d_in[0];
  p.y      = (const float *)d_in[1];
  p.points = (const float *)d_in[2];
  p.feat   = (const float *)d_in[3];
  p.Wq     = (const float *)d_in[4];
  p.Wpos1  = (const float *)d_in[5];
  p.Wpos2  = (const float *)d_in[6];
  p.gq = (const float *)d_in[10]; p.bq = (const float *)d_in[11];
  p.mq = (const float *)d_in[12]; p.vq = (const float *)d_in[13];
  p.gp = (const float *)d_in[14]; p.bp = (const float *)d_in[15];
  p.mp = (const float *)d_in[16]; p.vp = (const float *)d_in[17];
  p.WAf = WAf; p.WLf = WLf; p.WRf = WRf;
  p.baP = baP; p.bnf = bnf;
  p.out = (float *)d_out;

  fused_pt_attn<<<dim3(NB * NPT / 4), dim3(256), 0, stream>>>(p);
}